// Round 10
// baseline (1362.362 us; speedup 1.0000x reference)
//
#include <hip/hip_runtime.h>
#include <math.h>

// Persistent-kernel ResonatorABC scan — tagged dataflow + linear-bin exact select.
// Grid: 128 WGs x 256 threads (4 waves). WG w owns features [8w,8w+8) for ALL
// 128 rows; thread owns 4 (b,f): b = rg+32k, f = 8w+fl. WG w selects row w.
// Round-10: round-8 base (best: 1203us) + fused wave0 scan/locate (-2 barriers)
// + direct per-thread tau polling (-1 barrier, -LDS hop) + zero-sleep hot polls.
// Exact per-step min/max binning (adaptive window reverted — refine-risk).

#define T_STEPS 128
#define B_DIM   128
#define F_DIM   1024
#define NWG     128
#define NTH     256
#define BF      (B_DIM * F_DIM)

typedef unsigned long long ull;

__device__ __forceinline__ ull ld64(const ull* p) {
  return __hip_atomic_load(p, __ATOMIC_RELAXED, __HIP_MEMORY_SCOPE_AGENT);
}
__device__ __forceinline__ void st64(ull* p, ull v) {
  __hip_atomic_store(p, v, __ATOMIC_RELAXED, __HIP_MEMORY_SCOPE_AGENT);
}

extern "C" __global__ void __launch_bounds__(NTH)
ResonatorABC_82094004896068_kernel(
    const float* __restrict__ in_re, const float* __restrict__ in_im,
    const float* __restrict__ r_re_p, const float* __restrict__ r_im_p,
    const float* __restrict__ alpha_map, const float* __restrict__ lambda_map,
    float* __restrict__ out, ull* __restrict__ ws)
{
  const int tid  = threadIdx.x;
  const int wg   = blockIdx.x;
  const int fl   = tid & 7;         // feature-local index
  const int rg   = tid >> 3;        // row-group base (0..31); rows rg+32k
  const int f    = (wg << 3) + fl;  // global feature
  const int wid  = tid >> 6;        // wave id (0..3)
  const int lane = tid & 63;

  ull* score64 = ws;                // [B][F] {tag|score_bits}
  ull* tauB64  = ws + BF;           // [128]
  ull* tauC64  = ws + BF + 128;     // [128]

  __shared__ __align__(16) float pamp[4][8][4];   // wave partials: amp, amp2, unit_re, unit_im
  __shared__ __align__(16) float pev[4][8][2];    // wave partials: evB, evC
  __shared__ __align__(16) unsigned h[1024];      // histogram
  __shared__ unsigned wsum[4];                    // refine cross-wave scan
  __shared__ unsigned mmw[4][2];                  // per-wave min/max
  __shared__ unsigned tbin[4], tbase[4], tcnt[4]; // located rank bins
  __shared__ unsigned lcnt[4];                    // list counters
  __shared__ unsigned lists[4][256];              // extracted bin values
  __shared__ unsigned resv[4], resf[4];           // resolved rank values/flags
  __shared__ unsigned rmm[2];                     // refine min/max
  __shared__ unsigned t2[3];                      // refine located bin/base/cnt

  const float af = fminf(fmaxf(0.97f + 0.05f * tanhf(alpha_map[f]), 0.90f), 0.995f);
  const float lf = fminf(fmaxf(0.95f + 0.05f * tanhf(lambda_map[f]), 0.90f), 0.995f);
  const float rr = r_re_p[f];
  const float ri = r_im_p[f];
  const float c002 = cosf(0.02f);
  const float s002 = sinf(0.02f);

  float X_re[4] = {0.f,0.f,0.f,0.f}, X_im[4] = {0.f,0.f,0.f,0.f};
  float sA[4] = {0.f,0.f,0.f,0.f}, sB[4] = {0.f,0.f,0.f,0.f}, sC[4] = {0.f,0.f,0.f,0.f};
  float mu = 0.f, var = 0.01f, theta = 0.1f, ema_re = 0.f, ema_im = 0.f;

  int idx[4];
  float ur[4], ui[4];
  #pragma unroll
  for (int k = 0; k < 4; ++k) {
    idx[k] = (rg + 32 * k) * F_DIM + f;
    ur[k] = in_re[idx[k]];
    ui[k] = in_im[idx[k]];
  }

  const unsigned KR[4] = {255u, 256u, 767u, 768u};

  for (int t = 0; t < T_STEPS; ++t) {
    const ull want = (ull)(t + 1);

    *(uint4*)&h[4 * tid] = make_uint4(0u, 0u, 0u, 0u);   // covered by B1 / prev-step barriers

    // ---------------- Phase 1: elementwise + B-reduced stats + score ----------------
    float Xm_re[4], Xm_im[4], proj[4], amp[4], score[4];
    float a0 = 0.f, a1 = 0.f, a2 = 0.f, a3 = 0.f;
    #pragma unroll
    for (int k = 0; k < 4; ++k) {
      Xm_re[k] = af * X_re[k] + ur[k];
      Xm_im[k] = af * X_im[k] + ui[k];
      float amp2 = Xm_re[k] * Xm_re[k] + Xm_im[k] * Xm_im[k];
      amp[k] = sqrtf(amp2);
      float invamp = (amp[k] > 0.f) ? (1.0f / amp[k]) : 0.f;
      float un_re = (amp[k] > 0.f) ? (Xm_re[k] * invamp) : 1.0f;  // angle(0)=0 -> unit=1
      float un_im = Xm_im[k] * invamp;
      proj[k] = Xm_re[k] * rr + Xm_im[k] * ri;                    // Re(X_mid*conj(r))
      sA[k] = lf * sA[k] + proj[k];
      out[t * BF + idx[k]] = sA[k];
      a0 += amp[k]; a1 += amp2; a2 += un_re; a3 += un_im;
    }
    #pragma unroll
    for (int m = 8; m < 64; m <<= 1) {
      a0 += __shfl_xor(a0, m);
      a1 += __shfl_xor(a1, m);
      a2 += __shfl_xor(a2, m);
      a3 += __shfl_xor(a3, m);
    }
    if (lane < 8) { *(float4*)&pamp[wid][lane][0] = make_float4(a0, a1, a2, a3); }
    __syncthreads();                                   // B1
    float4 P0 = *(const float4*)&pamp[0][fl][0];
    float4 P1 = *(const float4*)&pamp[1][fl][0];
    float4 P2 = *(const float4*)&pamp[2][fl][0];
    float4 P3 = *(const float4*)&pamp[3][fl][0];
    float S0 = P0.x + P1.x + P2.x + P3.x;
    float S1 = P0.y + P1.y + P2.y + P3.y;
    float S2 = P0.z + P1.z + P2.z + P3.z;
    float S3 = P0.w + P1.w + P2.w + P3.w;
    float m1 = S0 * 0.0078125f;
    float m2 = S1 * 0.0078125f;
    mu = 0.9f * mu + 0.1f * m1;
    float vm = m2 - 2.f * mu * m1 + mu * mu;
    vm = fmaxf(vm, 0.f);
    var = 0.9f * var + 0.1f * vm;
    ema_re = 0.9f * ema_re + 0.1f * (S2 * 0.0078125f);
    ema_im = 0.9f * ema_im + 0.1f * (S3 * 0.0078125f);
    float plv = sqrtf(ema_re * ema_re + ema_im * ema_im);
    float sden = sqrtf(var) + 1e-3f;
    #pragma unroll
    for (int k = 0; k < 4; ++k) {
      float zs = (amp[k] - mu) / sden;
      score[k] = amp[k] + 0.5f * fabsf(zs) + 0.5f * (1.0f - plv);
      st64(&score64[idx[k]], (want << 32) | (ull)__float_as_uint(score[k]));
    }

    // prefetch next-step inputs; latency hidden behind select
    float ur_n[4] = {0.f,0.f,0.f,0.f}, ui_n[4] = {0.f,0.f,0.f,0.f};
    if (t + 1 < T_STEPS) {
      #pragma unroll
      for (int k = 0; k < 4; ++k) {
        ur_n[k] = in_re[(t + 1) * BF + idx[k]];
        ui_n[k] = in_im[(t + 1) * BF + idx[k]];
      }
    }

    // ---------------- Phase 2: hot-poll scores; exact min/max-bin select ----------------
    unsigned uval[4], bin[4];
    {
      const ull* sp0 = &score64[wg * F_DIM + tid];
      ull v[4]; bool ok[4] = {false, false, false, false};
      int remaining = 4;
      while (remaining) {
        #pragma unroll
        for (int k = 0; k < 4; ++k) if (!ok[k]) v[k] = ld64(sp0 + 256 * k);
        #pragma unroll
        for (int k = 0; k < 4; ++k) {
          if (!ok[k] && (v[k] >> 32) == want) { ok[k] = true; uval[k] = (unsigned)v[k]; --remaining; }
        }
      }
    }
    unsigned umin = min(min(uval[0], uval[1]), min(uval[2], uval[3]));
    unsigned umax = max(max(uval[0], uval[1]), max(uval[2], uval[3]));
    #pragma unroll
    for (int m = 1; m < 64; m <<= 1) {
      umin = min(umin, (unsigned)__shfl_xor((int)umin, m));
      umax = max(umax, (unsigned)__shfl_xor((int)umax, m));
    }
    if (lane == 0) { mmw[wid][0] = umin; mmw[wid][1] = umax; }
    if (tid < 4) { lcnt[tid] = 0u; resf[tid] = 0u; }
    __syncthreads();                                   // B2
    unsigned lo = min(min(mmw[0][0], mmw[1][0]), min(mmw[2][0], mmw[3][0]));
    unsigned hi = max(max(mmw[0][1], mmw[1][1]), max(mmw[2][1], mmw[3][1]));

    if (lo != hi) {
      ull rng = (ull)hi - (ull)lo + 1ull;
      ull inv = (1ull << 40) / rng;      // floor; monotone bin map, <=1023
      #pragma unroll
      for (int k = 0; k < 4; ++k) {
        bin[k] = (unsigned)((((ull)(uval[k] - lo)) * inv) >> 30);
        atomicAdd(&h[bin[k]], 1u);
      }
      __syncthreads();                                 // B3

      if (wid == 0) {   // fused scan + locate: 16 bins/lane in registers
        uint4 q0 = *(const uint4*)&h[16 * lane +  0];
        uint4 q1 = *(const uint4*)&h[16 * lane +  4];
        uint4 q2 = *(const uint4*)&h[16 * lane +  8];
        uint4 q3 = *(const uint4*)&h[16 * lane + 12];
        unsigned c16[16] = {q0.x,q0.y,q0.z,q0.w, q1.x,q1.y,q1.z,q1.w,
                            q2.x,q2.y,q2.z,q2.w, q3.x,q3.y,q3.z,q3.w};
        unsigned s16 = 0;
        #pragma unroll
        for (int i = 0; i < 16; ++i) s16 += c16[i];
        unsigned incl = s16;
        #pragma unroll
        for (int d = 1; d < 64; d <<= 1) {
          unsigned vv = __shfl_up(incl, d);
          if (lane >= d) incl += vv;
        }
        unsigned bacc = incl - s16;                    // exclusive base of lane's stripe
        #pragma unroll
        for (int i = 0; i < 16; ++i) {
          unsigned c = c16[i];
          if (c) {
            #pragma unroll
            for (int r = 0; r < 4; ++r) {
              if (bacc <= KR[r] && KR[r] < bacc + c) {
                tbin[r] = 16 * lane + i; tbase[r] = bacc; tcnt[r] = c;
              }
            }
          }
          bacc += c;
        }
      }
      __syncthreads();                                 // B4

      // build candidate lists (dedup: first list of each distinct bin; tbin non-decreasing)
      {
        unsigned b0 = tbin[0], b1 = tbin[1], b2 = tbin[2], b3 = tbin[3];
        #pragma unroll
        for (int k = 0; k < 4; ++k) {
          unsigned bk = bin[k], uv = uval[k];
          if (bk == b0) { unsigned s = atomicAdd(&lcnt[0], 1u); if (s < 256u) lists[0][s] = uv; }
          else if (bk == b1 && b1 != b0) { unsigned s = atomicAdd(&lcnt[1], 1u); if (s < 256u) lists[1][s] = uv; }
          else if (bk == b2 && b2 != b1) { unsigned s = atomicAdd(&lcnt[2], 1u); if (s < 256u) lists[2][s] = uv; }
          else if (bk == b3 && b3 != b2) { unsigned s = atomicAdd(&lcnt[3], 1u); if (s < 256u) lists[3][s] = uv; }
        }
      }
      __syncthreads();                                 // B5

      {   // wave j resolves rank j
        const int j = wid;
        int src = j;
        while (src > 0 && tbin[src - 1] == tbin[j]) --src;
        unsigned c = tcnt[j];
        if (c <= 256u) {
          unsigned kk = KR[j] - tbase[j];
          for (int bi = 0; bi < (int)c; bi += 64) {
            int i = bi + lane;
            if (i < (int)c) {
              unsigned e = lists[src][i];
              unsigned r = 0;
              for (int q = 0; q < (int)c; ++q) {
                unsigned x = lists[src][q];
                r += (x < e || (x == e && q < i)) ? 1u : 0u;
              }
              if (r == kk) { resv[j] = e; resf[j] = 1u; }
            }
          }
        }
      }
      __syncthreads();                                 // B6

      // rare exact refine for any unresolved rank (degenerate duplicate-heavy bins)
      for (int j = 0; j < 4; ++j) {
        if (resf[j]) continue;   // uniform
        bool inj[4];
        #pragma unroll
        for (int k = 0; k < 4; ++k) inj[k] = (bin[k] == tbin[j]);
        unsigned krem = KR[j] - tbase[j];
        for (int iter = 0; iter < 40; ++iter) {
          if (tid == 0) { rmm[0] = 0xFFFFFFFFu; rmm[1] = 0u; }
          __syncthreads();
          #pragma unroll
          for (int k = 0; k < 4; ++k)
            if (inj[k]) { atomicMin(&rmm[0], uval[k]); atomicMax(&rmm[1], uval[k]); }
          __syncthreads();
          unsigned wlo = rmm[0], whi = rmm[1];
          if (wlo == whi) { if (tid == 0) { resv[j] = wlo; resf[j] = 1u; } __syncthreads(); break; }
          *(uint4*)&h[4 * tid] = make_uint4(0u, 0u, 0u, 0u);
          __syncthreads();
          ull rng2 = (ull)whi - (ull)wlo + 1ull;
          ull inv2 = (1ull << 40) / rng2;
          unsigned nb[4];
          #pragma unroll
          for (int k = 0; k < 4; ++k) {
            nb[k] = inj[k] ? (unsigned)((((ull)(uval[k] - wlo)) * inv2) >> 30) : 0u;
            if (inj[k]) atomicAdd(&h[nb[k]], 1u);
          }
          __syncthreads();
          uint4 hc2 = *(const uint4*)&h[4 * tid];
          unsigned s42 = hc2.x + hc2.y + hc2.z + hc2.w;
          unsigned incl2 = s42;
          #pragma unroll
          for (int d = 1; d < 64; d <<= 1) {
            unsigned vv = __shfl_up(incl2, d);
            if (lane >= d) incl2 += vv;
          }
          if (lane == 63) wsum[wid] = incl2;
          if (tid == 0) lcnt[0] = 0u;
          __syncthreads();
          unsigned woff2 = 0u;
          for (int w = 0; w < 4; ++w) if (w < wid) woff2 += wsum[w];
          unsigned gexcl2 = woff2 + incl2 - s42;
          unsigned cv2[4] = {hc2.x, hc2.y, hc2.z, hc2.w};
          unsigned bb2[4];
          bb2[0] = gexcl2; bb2[1] = bb2[0] + cv2[0]; bb2[2] = bb2[1] + cv2[1]; bb2[3] = bb2[2] + cv2[2];
          #pragma unroll
          for (int i = 0; i < 4; ++i) {
            if (cv2[i] > 0u && bb2[i] <= krem && krem < bb2[i] + cv2[i]) {
              t2[0] = 4 * tid + i; t2[1] = bb2[i]; t2[2] = cv2[i];
            }
          }
          __syncthreads();
          unsigned nbin = t2[0], nbase = t2[1], ncnt = t2[2];
          bool newin[4];
          #pragma unroll
          for (int k = 0; k < 4; ++k) newin[k] = inj[k] && (nb[k] == nbin);
          if (ncnt <= 256u) {
            #pragma unroll
            for (int k = 0; k < 4; ++k)
              if (newin[k]) { unsigned s = atomicAdd(&lcnt[0], 1u); if (s < 256u) lists[0][s] = uval[k]; }
            __syncthreads();
            if (wid == 0) {
              unsigned kk2 = krem - nbase;
              for (int bi = 0; bi < (int)ncnt; bi += 64) {
                int i = bi + lane;
                if (i < (int)ncnt) {
                  unsigned e = lists[0][i];
                  unsigned r = 0;
                  for (int q = 0; q < (int)ncnt; ++q) {
                    unsigned x = lists[0][q];
                    r += (x < e || (x == e && q < i)) ? 1u : 0u;
                  }
                  if (r == kk2) { resv[j] = e; resf[j] = 1u; }
                }
              }
            }
            __syncthreads();
            break;
          }
          #pragma unroll
          for (int k = 0; k < 4; ++k) inj[k] = newin[k];
          krem -= nbase;
        }
      }
    } else {
      if (tid < 4) { resv[tid] = lo; resf[tid] = 1u; }
      __syncthreads();
    }

    // ---------------- tau publish (tid0) ----------------
    if (tid == 0) {
      float s255 = __uint_as_float(resv[0]);
      float s256 = __uint_as_float(resv[1]);
      float s767 = __uint_as_float(resv[2]);
      float s768 = __uint_as_float(resv[3]);
      float tb = 0.75f * s767 + 0.25f * s768;           // quantile(score, .75)
      float tc = -(0.75f * s256 + 0.25f * s255);        // quantile(-score, .75)
      st64(&tauB64[wg], (want << 32) | (ull)__float_as_uint(tb));
      st64(&tauC64[wg], (want << 32) | (ull)__float_as_uint(tc));
    }

    // ---------------- tau gather: each thread hot-polls its own 8 tau words ----------
    float tbv[4], tcv[4];
    {
      ull vb[4], vc[4]; bool okb[4] = {false,false,false,false}, okc[4] = {false,false,false,false};
      int remaining = 8;
      while (remaining) {
        #pragma unroll
        for (int k = 0; k < 4; ++k) {
          if (!okb[k]) vb[k] = ld64(&tauB64[rg + 32 * k]);
          if (!okc[k]) vc[k] = ld64(&tauC64[rg + 32 * k]);
        }
        #pragma unroll
        for (int k = 0; k < 4; ++k) {
          if (!okb[k] && (vb[k] >> 32) == want) { okb[k] = true; tbv[k] = __uint_as_float((unsigned)vb[k]); --remaining; }
          if (!okc[k] && (vc[k] >> 32) == want) { okc[k] = true; tcv[k] = __uint_as_float((unsigned)vc[k]); --remaining; }
        }
      }
    }

    // ---------------- Phase 3: gates, s-updates, events, theta/corr, reentry ----------
    float gB[4];
    float e0 = 0.f, e1 = 0.f;
    #pragma unroll
    for (int k = 0; k < 4; ++k) {
      float sc = score[k];
      gB[k] = 1.0f / (1.0f + expf(-5.0f * (sc - tbv[k])));
      float gC = 1.0f / (1.0f + expf(-5.0f * (-sc - tcv[k])));
      sB[k] = lf * sB[k] + proj[k] * gB[k];
      sC[k] = lf * sC[k] + proj[k] * gC;
      e0 += (sB[k] >= theta) ? 1.0f : 0.0f;
      e1 += (sC[k] >= theta) ? 1.0f : 0.0f;
    }
    #pragma unroll
    for (int m = 8; m < 64; m <<= 1) {
      e0 += __shfl_xor(e0, m);
      e1 += __shfl_xor(e1, m);
    }
    if (lane < 8) { pev[wid][lane][0] = e0; pev[wid][lane][1] = e1; }
    __syncthreads();                                   // B7
    float2 E0 = *(const float2*)&pev[0][fl][0];
    float2 E1 = *(const float2*)&pev[1][fl][0];
    float2 E2 = *(const float2*)&pev[2][fl][0];
    float2 E3 = *(const float2*)&pev[3][fl][0];
    float cB = E0.x + E1.x + E2.x + E3.x;
    float cC = E0.y + E1.y + E2.y + E3.y;
    float th1 = theta + 0.01f * (cB * 0.0078125f) - 0.01f * (cC * 0.0078125f);
    theta = fminf(fmaxf(th1 - 0.01f * (th1 - 0.1f), 0.01f), 10.0f);
    bool corr = (cB > 0.f);
    #pragma unroll
    for (int k = 0; k < 4; ++k) {
      float fac_re = corr ? (c002 + 0.1f * gB[k]) : 1.0f;
      float fac_im = corr ? s002 : 0.0f;
      X_re[k] = Xm_re[k] * fac_re - Xm_im[k] * fac_im;
      X_im[k] = Xm_re[k] * fac_im + Xm_im[k] * fac_re;
      ur[k] = ur_n[k]; ui[k] = ui_n[k];
    }
  }
}

extern "C" void kernel_launch(void* const* d_in, const int* in_sizes, int n_in,
                              void* d_out, int out_size, void* d_ws, size_t ws_size,
                              hipStream_t stream) {
  const float* in_re = (const float*)d_in[0];
  const float* in_im = (const float*)d_in[1];
  const float* r_re  = (const float*)d_in[2];
  const float* r_im  = (const float*)d_in[3];
  const float* amap  = (const float*)d_in[4];
  const float* lmap  = (const float*)d_in[5];
  float* out = (float*)d_out;
  ull* ws = (ull*)d_ws;
  // zero all tag words (scores + taus) so no stale tag can match
  hipMemsetAsync(d_ws, 0, (size_t)(BF + 256) * 8, stream);
  hipLaunchKernelGGL(ResonatorABC_82094004896068_kernel,
                     dim3(NWG), dim3(NTH), 0, stream,
                     in_re, in_im, r_re, r_im, amap, lmap, out, ws);
}

// Round 11
// 1281.614 us; speedup vs baseline: 1.0630x; 1.0630x over previous
//
#include <hip/hip_runtime.h>
#include <math.h>

// Persistent-kernel ResonatorABC scan — 32-bit PARITY-TAGGED dataflow + linear-bin
// exact select. Grid: 128 WGs x 256 threads (4 waves). WG w owns features
// [8w,8w+8) for ALL 128 rows; thread owns 4 (b,f): b=rg+32k, f=8w+fl. WG w
// runs the exact rank select {255,256,767,768} for row w.
// Exchange words are 32-bit: payload = positive-float bits (score>0, taus
// stored positive), tag = step parity in bit31. Coherence order makes parity
// unambiguous (a poller that saw step t-1's value cannot read t-2's).
// Halves exchange bytes + doubles 64B-line packing vs the 64-bit tag scheme —
// targets the measured fabric-congestion floor of the two rendezvous per step.

#define T_STEPS 128
#define B_DIM   128
#define F_DIM   1024
#define NWG     128
#define NTH     256
#define BF      (B_DIM * F_DIM)

typedef unsigned long long ull;

__device__ __forceinline__ unsigned ld32(const unsigned* p) {
  return __hip_atomic_load(p, __ATOMIC_RELAXED, __HIP_MEMORY_SCOPE_AGENT);
}
__device__ __forceinline__ void st32(unsigned* p, unsigned v) {
  __hip_atomic_store(p, v, __ATOMIC_RELAXED, __HIP_MEMORY_SCOPE_AGENT);
}

extern "C" __global__ void __launch_bounds__(NTH)
ResonatorABC_82094004896068_kernel(
    const float* __restrict__ in_re, const float* __restrict__ in_im,
    const float* __restrict__ r_re_p, const float* __restrict__ r_im_p,
    const float* __restrict__ alpha_map, const float* __restrict__ lambda_map,
    float* __restrict__ out, unsigned* __restrict__ ws)
{
  const int tid  = threadIdx.x;
  const int wg   = blockIdx.x;
  const int fl   = tid & 7;         // feature-local index
  const int rg   = tid >> 3;        // row-group base (0..31); rows rg+32k
  const int f    = (wg << 3) + fl;  // global feature
  const int wid  = tid >> 6;        // wave id (0..3)
  const int lane = tid & 63;

  unsigned* score32 = ws;           // [B][F] parity-tagged score bits
  unsigned* tauB32  = ws + BF;      // [128]
  unsigned* tauC32  = ws + BF + 128;// [128] (stored positive; tc = -value)

  __shared__ __align__(16) float pamp[4][8][4];   // wave partials: amp, amp2, unit_re, unit_im
  __shared__ __align__(16) float pfin[8][4];      // final per-feature sums
  __shared__ __align__(16) float pev[4][8][2];    // wave partials: evB, evC
  __shared__ __align__(16) float evfin[8][2];     // final per-feature event sums
  __shared__ __align__(16) unsigned h[1024];      // histogram (1024 bins)
  __shared__ unsigned wsum[4];                    // per-wave scan totals
  __shared__ unsigned mmw[4][2];                  // per-wave min/max
  __shared__ unsigned tbin[4], tbase[4], tcnt[4]; // located rank bins
  __shared__ unsigned lcnt[4];                    // list counters
  __shared__ unsigned lists[4][256];              // extracted bin values
  __shared__ unsigned resv[4], resf[4];           // resolved rank values/flags
  __shared__ unsigned rmm[2];                     // refine min/max
  __shared__ unsigned t2[3];                      // refine located bin/base/cnt
  __shared__ float tauLds[256];                   // gathered taus (tauB | tauC-positive)

  const float af = fminf(fmaxf(0.97f + 0.05f * tanhf(alpha_map[f]), 0.90f), 0.995f);
  const float lf = fminf(fmaxf(0.95f + 0.05f * tanhf(lambda_map[f]), 0.90f), 0.995f);
  const float rr = r_re_p[f];
  const float ri = r_im_p[f];
  const float c002 = cosf(0.02f);
  const float s002 = sinf(0.02f);

  float X_re[4] = {0.f,0.f,0.f,0.f}, X_im[4] = {0.f,0.f,0.f,0.f};
  float sA[4] = {0.f,0.f,0.f,0.f}, sB[4] = {0.f,0.f,0.f,0.f}, sC[4] = {0.f,0.f,0.f,0.f};
  float mu = 0.f, var = 0.01f, theta = 0.1f, ema_re = 0.f, ema_im = 0.f;

  int idx[4];
  float ur[4], ui[4];
  #pragma unroll
  for (int k = 0; k < 4; ++k) {
    idx[k] = (rg + 32 * k) * F_DIM + f;
    ur[k] = in_re[idx[k]];
    ui[k] = in_im[idx[k]];
  }

  const unsigned KR[4] = {255u, 256u, 767u, 768u};

  for (int t = 0; t < T_STEPS; ++t) {
    const unsigned par = (unsigned)((t + 1) & 1);          // tag parity
    const unsigned tagbit = par << 31;

    *(uint4*)&h[4 * tid] = make_uint4(0u, 0u, 0u, 0u);     // covered by phase-1 syncs

    // ---------------- Phase 1: elementwise + B-reduced stats + score ----------------
    float Xm_re[4], Xm_im[4], proj[4], amp[4], score[4];
    float a0 = 0.f, a1 = 0.f, a2 = 0.f, a3 = 0.f;
    #pragma unroll
    for (int k = 0; k < 4; ++k) {
      Xm_re[k] = af * X_re[k] + ur[k];
      Xm_im[k] = af * X_im[k] + ui[k];
      float amp2 = Xm_re[k] * Xm_re[k] + Xm_im[k] * Xm_im[k];
      amp[k] = sqrtf(amp2);
      float invamp = (amp[k] > 0.f) ? (1.0f / amp[k]) : 0.f;
      float un_re = (amp[k] > 0.f) ? (Xm_re[k] * invamp) : 1.0f;  // angle(0)=0 -> unit=1
      float un_im = Xm_im[k] * invamp;
      proj[k] = Xm_re[k] * rr + Xm_im[k] * ri;                    // Re(X_mid*conj(r))
      sA[k] = lf * sA[k] + proj[k];
      out[t * BF + idx[k]] = sA[k];
      a0 += amp[k]; a1 += amp2; a2 += un_re; a3 += un_im;
    }
    #pragma unroll
    for (int m = 8; m < 64; m <<= 1) {
      a0 += __shfl_xor(a0, m);
      a1 += __shfl_xor(a1, m);
      a2 += __shfl_xor(a2, m);
      a3 += __shfl_xor(a3, m);
    }
    if (lane < 8) { *(float4*)&pamp[wid][lane][0] = make_float4(a0, a1, a2, a3); }
    __syncthreads();
    if (tid < 32) {   // summers: one per (feature, quantity)
      int sfl = tid >> 2, q = tid & 3;
      pfin[sfl][q] = pamp[0][sfl][q] + pamp[1][sfl][q] + pamp[2][sfl][q] + pamp[3][sfl][q];
    }
    __syncthreads();
    float4 SS = *(const float4*)&pfin[fl][0];
    float m1 = SS.x * 0.0078125f;      // mean(amp)
    float m2 = SS.y * 0.0078125f;      // mean(amp^2)
    mu = 0.9f * mu + 0.1f * m1;
    float vm = m2 - 2.f * mu * m1 + mu * mu;
    vm = fmaxf(vm, 0.f);
    var = 0.9f * var + 0.1f * vm;
    ema_re = 0.9f * ema_re + 0.1f * (SS.z * 0.0078125f);
    ema_im = 0.9f * ema_im + 0.1f * (SS.w * 0.0078125f);
    float plv = sqrtf(ema_re * ema_re + ema_im * ema_im);
    float sden = sqrtf(var) + 1e-3f;
    #pragma unroll
    for (int k = 0; k < 4; ++k) {
      float zs = (amp[k] - mu) / sden;
      score[k] = amp[k] + 0.5f * fabsf(zs) + 0.5f * (1.0f - plv);   // > 0 always
      st32(&score32[idx[k]], __float_as_uint(score[k]) | tagbit);
    }

    // prefetch next-step inputs; latency hidden behind select
    float ur_n[4] = {0.f,0.f,0.f,0.f}, ui_n[4] = {0.f,0.f,0.f,0.f};
    if (t + 1 < T_STEPS) {
      #pragma unroll
      for (int k = 0; k < 4; ++k) {
        ur_n[k] = in_re[(t + 1) * BF + idx[k]];
        ui_n[k] = in_im[(t + 1) * BF + idx[k]];
      }
    }

    // ---------------- Phase 2: poll scores (concurrent, sleep(1)); exact select ----------
    unsigned uval[4], bin[4];
    {
      const unsigned* sp0 = &score32[wg * F_DIM + tid];
      unsigned v[4]; bool ok[4] = {false, false, false, false};
      int remaining = 4;
      while (remaining) {
        #pragma unroll
        for (int k = 0; k < 4; ++k) if (!ok[k]) v[k] = ld32(sp0 + 256 * k);
        #pragma unroll
        for (int k = 0; k < 4; ++k) {
          if (!ok[k] && (v[k] >> 31) == par) { ok[k] = true; uval[k] = v[k] & 0x7FFFFFFFu; --remaining; }
        }
        if (remaining) __builtin_amdgcn_s_sleep(1);
      }
    }
    unsigned umin = min(min(uval[0], uval[1]), min(uval[2], uval[3]));
    unsigned umax = max(max(uval[0], uval[1]), max(uval[2], uval[3]));
    #pragma unroll
    for (int m = 1; m < 64; m <<= 1) {
      umin = min(umin, (unsigned)__shfl_xor((int)umin, m));
      umax = max(umax, (unsigned)__shfl_xor((int)umax, m));
    }
    if (lane == 0) { mmw[wid][0] = umin; mmw[wid][1] = umax; }
    if (tid < 4) { lcnt[tid] = 0u; resf[tid] = 0u; }
    __syncthreads();
    unsigned lo = min(min(mmw[0][0], mmw[1][0]), min(mmw[2][0], mmw[3][0]));
    unsigned hi = max(max(mmw[0][1], mmw[1][1]), max(mmw[2][1], mmw[3][1]));

    if (lo != hi) {
      ull rng = (ull)hi - (ull)lo + 1ull;
      ull inv = (1ull << 40) / rng;      // floor; monotone bin map, <=1023
      #pragma unroll
      for (int k = 0; k < 4; ++k) {
        bin[k] = (unsigned)((((ull)(uval[k] - lo)) * inv) >> 30);
        atomicAdd(&h[bin[k]], 1u);
      }
      __syncthreads();
      // scan: thread owns 4 consecutive bins (2-stage, low-conflict)
      uint4 hc = *(const uint4*)&h[4 * tid];
      unsigned s4 = hc.x + hc.y + hc.z + hc.w;
      unsigned incl = s4;
      #pragma unroll
      for (int d = 1; d < 64; d <<= 1) {
        unsigned vv = __shfl_up(incl, d);
        if (lane >= d) incl += vv;
      }
      if (lane == 63) wsum[wid] = incl;
      __syncthreads();
      unsigned woff = 0u;
      for (int w = 0; w < 4; ++w) if (w < wid) woff += wsum[w];
      unsigned gexcl = woff + incl - s4;       // exclusive base of my 4-bin group
      unsigned cv[4] = {hc.x, hc.y, hc.z, hc.w};
      unsigned bb[4];
      bb[0] = gexcl; bb[1] = bb[0] + cv[0]; bb[2] = bb[1] + cv[1]; bb[3] = bb[2] + cv[2];
      #pragma unroll
      for (int i = 0; i < 4; ++i) {
        if (cv[i] > 0u) {
          #pragma unroll
          for (int r = 0; r < 4; ++r) {
            if (bb[i] <= KR[r] && KR[r] < bb[i] + cv[i]) {
              tbin[r] = 4 * tid + i; tbase[r] = bb[i]; tcnt[r] = cv[i];
            }
          }
        }
      }
      __syncthreads();
      // build candidate lists (dedup: first list of each distinct bin; tbin non-decreasing)
      {
        unsigned b0 = tbin[0], b1 = tbin[1], b2 = tbin[2], b3 = tbin[3];
        #pragma unroll
        for (int k = 0; k < 4; ++k) {
          unsigned bk = bin[k], uv = uval[k];
          if (bk == b0) { unsigned s = atomicAdd(&lcnt[0], 1u); if (s < 256u) lists[0][s] = uv; }
          else if (bk == b1 && b1 != b0) { unsigned s = atomicAdd(&lcnt[1], 1u); if (s < 256u) lists[1][s] = uv; }
          else if (bk == b2 && b2 != b1) { unsigned s = atomicAdd(&lcnt[2], 1u); if (s < 256u) lists[2][s] = uv; }
          else if (bk == b3 && b3 != b2) { unsigned s = atomicAdd(&lcnt[3], 1u); if (s < 256u) lists[3][s] = uv; }
        }
      }
      __syncthreads();
      {   // wave j resolves rank j (all 4 waves busy)
        const int j = wid;
        int src = j;
        while (src > 0 && tbin[src - 1] == tbin[j]) --src;
        unsigned c = tcnt[j];
        if (c <= 256u) {
          unsigned kk = KR[j] - tbase[j];
          for (int bi = 0; bi < (int)c; bi += 64) {
            int i = bi + lane;
            if (i < (int)c) {
              unsigned e = lists[src][i];
              unsigned r = 0;
              for (int q = 0; q < (int)c; ++q) {
                unsigned x = lists[src][q];
                r += (x < e || (x == e && q < i)) ? 1u : 0u;
              }
              if (r == kk) { resv[j] = e; resf[j] = 1u; }
            }
          }
        }
      }
      __syncthreads();
      // rare exact refine for any unresolved rank (degenerate duplicate-heavy bins)
      for (int j = 0; j < 4; ++j) {
        if (resf[j]) continue;   // uniform
        bool inj[4];
        #pragma unroll
        for (int k = 0; k < 4; ++k) inj[k] = (bin[k] == tbin[j]);
        unsigned krem = KR[j] - tbase[j];
        for (int iter = 0; iter < 40; ++iter) {
          if (tid == 0) { rmm[0] = 0xFFFFFFFFu; rmm[1] = 0u; }
          __syncthreads();
          #pragma unroll
          for (int k = 0; k < 4; ++k)
            if (inj[k]) { atomicMin(&rmm[0], uval[k]); atomicMax(&rmm[1], uval[k]); }
          __syncthreads();
          unsigned wlo = rmm[0], whi = rmm[1];
          if (wlo == whi) { if (tid == 0) { resv[j] = wlo; resf[j] = 1u; } __syncthreads(); break; }
          *(uint4*)&h[4 * tid] = make_uint4(0u, 0u, 0u, 0u);
          __syncthreads();
          ull rng2 = (ull)whi - (ull)wlo + 1ull;
          ull inv2 = (1ull << 40) / rng2;
          unsigned nb[4];
          #pragma unroll
          for (int k = 0; k < 4; ++k) {
            nb[k] = inj[k] ? (unsigned)((((ull)(uval[k] - wlo)) * inv2) >> 30) : 0u;
            if (inj[k]) atomicAdd(&h[nb[k]], 1u);
          }
          __syncthreads();
          uint4 hc2 = *(const uint4*)&h[4 * tid];
          unsigned s42 = hc2.x + hc2.y + hc2.z + hc2.w;
          unsigned incl2 = s42;
          #pragma unroll
          for (int d = 1; d < 64; d <<= 1) {
            unsigned vv = __shfl_up(incl2, d);
            if (lane >= d) incl2 += vv;
          }
          if (lane == 63) wsum[wid] = incl2;
          if (tid == 0) lcnt[0] = 0u;
          __syncthreads();
          unsigned woff2 = 0u;
          for (int w = 0; w < 4; ++w) if (w < wid) woff2 += wsum[w];
          unsigned gexcl2 = woff2 + incl2 - s42;
          unsigned cv2[4] = {hc2.x, hc2.y, hc2.z, hc2.w};
          unsigned bb2[4];
          bb2[0] = gexcl2; bb2[1] = bb2[0] + cv2[0]; bb2[2] = bb2[1] + cv2[1]; bb2[3] = bb2[2] + cv2[2];
          #pragma unroll
          for (int i = 0; i < 4; ++i) {
            if (cv2[i] > 0u && bb2[i] <= krem && krem < bb2[i] + cv2[i]) {
              t2[0] = 4 * tid + i; t2[1] = bb2[i]; t2[2] = cv2[i];
            }
          }
          __syncthreads();
          unsigned nbin = t2[0], nbase = t2[1], ncnt = t2[2];
          bool newin[4];
          #pragma unroll
          for (int k = 0; k < 4; ++k) newin[k] = inj[k] && (nb[k] == nbin);
          if (ncnt <= 256u) {
            #pragma unroll
            for (int k = 0; k < 4; ++k)
              if (newin[k]) { unsigned s = atomicAdd(&lcnt[0], 1u); if (s < 256u) lists[0][s] = uval[k]; }
            __syncthreads();
            if (wid == 0) {
              unsigned kk2 = krem - nbase;
              for (int bi = 0; bi < (int)ncnt; bi += 64) {
                int i = bi + lane;
                if (i < (int)ncnt) {
                  unsigned e = lists[0][i];
                  unsigned r = 0;
                  for (int q = 0; q < (int)ncnt; ++q) {
                    unsigned x = lists[0][q];
                    r += (x < e || (x == e && q < i)) ? 1u : 0u;
                  }
                  if (r == kk2) { resv[j] = e; resf[j] = 1u; }
                }
              }
            }
            __syncthreads();
            break;
          }
          #pragma unroll
          for (int k = 0; k < 4; ++k) inj[k] = newin[k];
          krem -= nbase;
        }
      }
    } else {
      if (tid < 4) { resv[tid] = lo; resf[tid] = 1u; }
      __syncthreads();
    }

    // ---------------- tau publish (tid0; both stored POSITIVE, parity-tagged) ----------
    if (tid == 0) {
      float s255 = __uint_as_float(resv[0]);
      float s256 = __uint_as_float(resv[1]);
      float s767 = __uint_as_float(resv[2]);
      float s768 = __uint_as_float(resv[3]);
      float tbq = 0.75f * s767 + 0.25f * s768;          // quantile(score,.75) > 0
      float tcq = 0.75f * s256 + 0.25f * s255;          // -quantile(-score,.75) > 0
      st32(&tauB32[wg], __float_as_uint(tbq) | tagbit);
      st32(&tauC32[wg], __float_as_uint(tcq) | tagbit);
    }

    // ---------------- tau gather: 256 pollers (one word each) -> LDS broadcast ----------
    {
      const unsigned* src = (tid < 128) ? &tauB32[tid] : &tauC32[tid - 128];
      unsigned v2 = ld32(src);
      while ((v2 >> 31) != par) { __builtin_amdgcn_s_sleep(1); v2 = ld32(src); }
      tauLds[tid] = __uint_as_float(v2 & 0x7FFFFFFFu);
    }
    __syncthreads();

    // ---------------- Phase 3: gates, s-updates, events, theta/corr, reentry ----------
    float gB[4];
    float e0 = 0.f, e1 = 0.f;
    #pragma unroll
    for (int k = 0; k < 4; ++k) {
      float tb = tauLds[rg + 32 * k];
      float q  = tauLds[128 + rg + 32 * k];    // tcq; reference tc = -q
      float sc = score[k];
      gB[k] = 1.0f / (1.0f + expf(-5.0f * (sc - tb)));
      float gC = 1.0f / (1.0f + expf(-5.0f * (q - sc)));   // == sigmoid(5*(-sc - tc))
      sB[k] = lf * sB[k] + proj[k] * gB[k];
      sC[k] = lf * sC[k] + proj[k] * gC;
      e0 += (sB[k] >= theta) ? 1.0f : 0.0f;
      e1 += (sC[k] >= theta) ? 1.0f : 0.0f;
    }
    #pragma unroll
    for (int m = 8; m < 64; m <<= 1) {
      e0 += __shfl_xor(e0, m);
      e1 += __shfl_xor(e1, m);
    }
    if (lane < 8) { pev[wid][lane][0] = e0; pev[wid][lane][1] = e1; }
    __syncthreads();
    if (tid < 16) {   // summers
      int sfl = tid >> 1, q = tid & 1;
      evfin[sfl][q] = pev[0][sfl][q] + pev[1][sfl][q] + pev[2][sfl][q] + pev[3][sfl][q];
    }
    __syncthreads();
    float cB = evfin[fl][0];
    float cC = evfin[fl][1];
    float th1 = theta + 0.01f * (cB * 0.0078125f) - 0.01f * (cC * 0.0078125f);
    theta = fminf(fmaxf(th1 - 0.01f * (th1 - 0.1f), 0.01f), 10.0f);
    bool corr = (cB > 0.f);
    #pragma unroll
    for (int k = 0; k < 4; ++k) {
      float fac_re = corr ? (c002 + 0.1f * gB[k]) : 1.0f;
      float fac_im = corr ? s002 : 0.0f;
      X_re[k] = Xm_re[k] * fac_re - Xm_im[k] * fac_im;
      X_im[k] = Xm_re[k] * fac_im + Xm_im[k] * fac_re;
      ur[k] = ur_n[k]; ui[k] = ui_n[k];
    }
  }
}

extern "C" void kernel_launch(void* const* d_in, const int* in_sizes, int n_in,
                              void* d_out, int out_size, void* d_ws, size_t ws_size,
                              hipStream_t stream) {
  const float* in_re = (const float*)d_in[0];
  const float* in_im = (const float*)d_in[1];
  const float* r_re  = (const float*)d_in[2];
  const float* r_im  = (const float*)d_in[3];
  const float* amap  = (const float*)d_in[4];
  const float* lmap  = (const float*)d_in[5];
  float* out = (float*)d_out;
  unsigned* ws = (unsigned*)d_ws;
  // zero all tagged words: sign bit 0 != parity 1 expected at t=0 -> no false match
  hipMemsetAsync(d_ws, 0, (size_t)(BF + 256) * 4, stream);
  hipLaunchKernelGGL(ResonatorABC_82094004896068_kernel,
                     dim3(NWG), dim3(NTH), 0, stream,
                     in_re, in_im, r_re, r_im, amap, lmap, out, ws);
}

// Round 12
// 1097.831 us; speedup vs baseline: 1.2410x; 1.1674x over previous
//
#include <hip/hip_runtime.h>
#include <math.h>

// Persistent-kernel ResonatorABC scan — tagged dataflow + linear-bin exact select
// + per-consumer TAU MAILBOXES (writer-side fan-out).
// EXACT REVERT to the round-8 configuration — the best measured (1203 us).
// Rounds 9-11 established: backoff sleeps regress (+detection latency),
// hot-polling regresses (fabric congestion slows producers), 32-bit parity
// words regress (despite halved traffic). The step floor is set by the two
// dependent cross-XCD rendezvous latencies, not by traffic volume.
// Grid: 128 WGs x 256 threads (4 waves). WG w owns features [8w,8w+8) for ALL
// 128 rows; each thread owns 4 (b,f) elements: b = rg+32k, f = 8w+fl.

#define T_STEPS 128
#define B_DIM   128
#define F_DIM   1024
#define NWG     128
#define NTH     256
#define BF      (B_DIM * F_DIM)

typedef unsigned long long ull;

__device__ __forceinline__ ull ld64(const ull* p) {
  return __hip_atomic_load(p, __ATOMIC_RELAXED, __HIP_MEMORY_SCOPE_AGENT);
}
__device__ __forceinline__ void st64(ull* p, ull v) {
  __hip_atomic_store(p, v, __ATOMIC_RELAXED, __HIP_MEMORY_SCOPE_AGENT);
}

extern "C" __global__ void __launch_bounds__(NTH)
ResonatorABC_82094004896068_kernel(
    const float* __restrict__ in_re, const float* __restrict__ in_im,
    const float* __restrict__ r_re_p, const float* __restrict__ r_im_p,
    const float* __restrict__ alpha_map, const float* __restrict__ lambda_map,
    float* __restrict__ out, ull* __restrict__ ws)
{
  const int tid  = threadIdx.x;
  const int wg   = blockIdx.x;
  const int fl   = tid & 7;         // feature-local index
  const int rg   = tid >> 3;        // row-group base (0..31); rows rg+32k
  const int f    = (wg << 3) + fl;  // global feature
  const int wid  = tid >> 6;        // wave id (0..3)
  const int lane = tid & 63;

  ull* score64 = ws;                // [B][F] {tag|score_bits}
  ull* taubox  = ws + BF;           // [128 consumers][256 slots] {tag|tau_bits}
                                    // slot b: tauB row b; slot 128+b: tauC row b

  __shared__ __align__(16) float pamp[4][8][4];   // wave partials: amp, amp2, unit_re, unit_im
  __shared__ __align__(16) float pfin[8][4];      // final per-feature sums
  __shared__ __align__(16) float pev[4][8][2];    // wave partials: evB, evC
  __shared__ __align__(16) float evfin[8][2];     // final per-feature event sums
  __shared__ __align__(16) unsigned h[1024];      // histogram (1024 bins)
  __shared__ unsigned wsum[4];                    // per-wave scan totals
  __shared__ unsigned mmw[4][2];                  // per-wave min/max
  __shared__ unsigned tbin[4], tbase[4], tcnt[4]; // located rank bins
  __shared__ unsigned lcnt[4];                    // list counters
  __shared__ unsigned lists[4][256];              // extracted bin values
  __shared__ unsigned resv[4], resf[4];           // resolved rank values/flags
  __shared__ unsigned rmm[2];                     // refine min/max
  __shared__ unsigned t2[3];                      // refine located bin/base/cnt
  __shared__ float tauLds[256];                   // gathered taus

  const float af = fminf(fmaxf(0.97f + 0.05f * tanhf(alpha_map[f]), 0.90f), 0.995f);
  const float lf = fminf(fmaxf(0.95f + 0.05f * tanhf(lambda_map[f]), 0.90f), 0.995f);
  const float rr = r_re_p[f];
  const float ri = r_im_p[f];
  const float c002 = cosf(0.02f);
  const float s002 = sinf(0.02f);

  // per-element carried state (4 rows of feature f)
  float X_re[4] = {0.f,0.f,0.f,0.f}, X_im[4] = {0.f,0.f,0.f,0.f};
  float sA[4] = {0.f,0.f,0.f,0.f}, sB[4] = {0.f,0.f,0.f,0.f}, sC[4] = {0.f,0.f,0.f,0.f};
  // per-feature carried state (single copy)
  float mu = 0.f, var = 0.01f, theta = 0.1f, ema_re = 0.f, ema_im = 0.f;

  int idx[4];
  float ur[4], ui[4];
  #pragma unroll
  for (int k = 0; k < 4; ++k) {
    idx[k] = (rg + 32 * k) * F_DIM + f;
    ur[k] = in_re[idx[k]];
    ui[k] = in_im[idx[k]];
  }

  const unsigned KR[4] = {255u, 256u, 767u, 768u};

  for (int t = 0; t < T_STEPS; ++t) {
    const ull want = (ull)(t + 1);

    *(uint4*)&h[4 * tid] = make_uint4(0u, 0u, 0u, 0u);   // zero hist (covered by phase-1 syncs)

    // ---------------- Phase 1: elementwise + B-reduced stats + score ----------------
    float Xm_re[4], Xm_im[4], proj[4], amp[4], score[4];
    float a0 = 0.f, a1 = 0.f, a2 = 0.f, a3 = 0.f;
    #pragma unroll
    for (int k = 0; k < 4; ++k) {
      Xm_re[k] = af * X_re[k] + ur[k];
      Xm_im[k] = af * X_im[k] + ui[k];
      float amp2 = Xm_re[k] * Xm_re[k] + Xm_im[k] * Xm_im[k];
      amp[k] = sqrtf(amp2);
      float invamp = (amp[k] > 0.f) ? (1.0f / amp[k]) : 0.f;
      float un_re = (amp[k] > 0.f) ? (Xm_re[k] * invamp) : 1.0f;  // angle(0)=0 -> unit=1
      float un_im = Xm_im[k] * invamp;
      proj[k] = Xm_re[k] * rr + Xm_im[k] * ri;                    // Re(X_mid*conj(r))
      sA[k] = lf * sA[k] + proj[k];
      out[t * BF + idx[k]] = sA[k];
      a0 += amp[k]; a1 += amp2; a2 += un_re; a3 += un_im;
    }
    #pragma unroll
    for (int m = 8; m < 64; m <<= 1) {   // reduce over row-groups within wave
      a0 += __shfl_xor(a0, m);
      a1 += __shfl_xor(a1, m);
      a2 += __shfl_xor(a2, m);
      a3 += __shfl_xor(a3, m);
    }
    if (lane < 8) { *(float4*)&pamp[wid][lane][0] = make_float4(a0, a1, a2, a3); }
    __syncthreads();
    if (tid < 32) {   // summers: one per (feature, quantity)
      int sfl = tid >> 2, q = tid & 3;
      pfin[sfl][q] = pamp[0][sfl][q] + pamp[1][sfl][q] + pamp[2][sfl][q] + pamp[3][sfl][q];
    }
    __syncthreads();
    float4 SS = *(const float4*)&pfin[fl][0];
    float m1 = SS.x * 0.0078125f;      // mean(amp)
    float m2 = SS.y * 0.0078125f;      // mean(amp^2)
    mu = 0.9f * mu + 0.1f * m1;
    float vm = m2 - 2.f * mu * m1 + mu * mu;
    vm = fmaxf(vm, 0.f);
    var = 0.9f * var + 0.1f * vm;
    ema_re = 0.9f * ema_re + 0.1f * (SS.z * 0.0078125f);
    ema_im = 0.9f * ema_im + 0.1f * (SS.w * 0.0078125f);
    float plv = sqrtf(ema_re * ema_re + ema_im * ema_im);
    float sden = sqrtf(var) + 1e-3f;
    #pragma unroll
    for (int k = 0; k < 4; ++k) {
      float zs = (amp[k] - mu) / sden;
      score[k] = amp[k] + 0.5f * fabsf(zs) + 0.5f * (1.0f - plv);
      st64(&score64[idx[k]], (want << 32) | (ull)__float_as_uint(score[k]));
    }

    // prefetch next-step inputs; latency hidden behind select
    float ur_n[4] = {0.f,0.f,0.f,0.f}, ui_n[4] = {0.f,0.f,0.f,0.f};
    if (t + 1 < T_STEPS) {
      #pragma unroll
      for (int k = 0; k < 4; ++k) {
        ur_n[k] = in_re[(t + 1) * BF + idx[k]];
        ui_n[k] = in_im[(t + 1) * BF + idx[k]];
      }
    }

    // ---------------- Phase 2: exact select of ranks {255,256,767,768} for row wg ----
    unsigned uval[4], bin[4];
    {
      // concurrent 4-way poll: all 4 loads in flight, re-poll only stale words
      const ull* sp0 = &score64[wg * F_DIM + tid];
      ull v[4]; bool ok[4] = {false, false, false, false};
      int remaining = 4;
      while (remaining) {
        #pragma unroll
        for (int k = 0; k < 4; ++k) if (!ok[k]) v[k] = ld64(sp0 + 256 * k);
        #pragma unroll
        for (int k = 0; k < 4; ++k) {
          if (!ok[k] && (v[k] >> 32) == want) { ok[k] = true; uval[k] = (unsigned)v[k]; --remaining; }
        }
        if (remaining) __builtin_amdgcn_s_sleep(1);
      }
    }
    unsigned umin = min(min(uval[0], uval[1]), min(uval[2], uval[3]));
    unsigned umax = max(max(uval[0], uval[1]), max(uval[2], uval[3]));
    #pragma unroll
    for (int m = 1; m < 64; m <<= 1) {
      umin = min(umin, (unsigned)__shfl_xor((int)umin, m));
      umax = max(umax, (unsigned)__shfl_xor((int)umax, m));
    }
    if (lane == 0) { mmw[wid][0] = umin; mmw[wid][1] = umax; }
    __syncthreads();
    unsigned lo = min(min(mmw[0][0], mmw[1][0]), min(mmw[2][0], mmw[3][0]));
    unsigned hi = max(max(mmw[0][1], mmw[1][1]), max(mmw[2][1], mmw[3][1]));

    if (lo != hi) {
      ull rng = (ull)hi - (ull)lo + 1ull;
      ull inv = (1ull << 40) / rng;      // floor; bin map monotone, bounded <=1023
      #pragma unroll
      for (int k = 0; k < 4; ++k) {
        bin[k] = (unsigned)((((ull)(uval[k] - lo)) * inv) >> 30);
        atomicAdd(&h[bin[k]], 1u);
      }
      if (tid < 4) { lcnt[tid] = 0u; resf[tid] = 0u; }
      __syncthreads();
      // scan: thread owns 4 consecutive bins
      uint4 hc = *(const uint4*)&h[4 * tid];
      unsigned s4 = hc.x + hc.y + hc.z + hc.w;
      unsigned incl = s4;
      #pragma unroll
      for (int d = 1; d < 64; d <<= 1) {
        unsigned vv = __shfl_up(incl, d);
        if (lane >= d) incl += vv;
      }
      if (lane == 63) wsum[wid] = incl;
      __syncthreads();
      unsigned woff = 0u;
      for (int w = 0; w < 4; ++w) if (w < wid) woff += wsum[w];
      unsigned gexcl = woff + incl - s4;       // exclusive base of my 4-bin group
      unsigned cv[4] = {hc.x, hc.y, hc.z, hc.w};
      unsigned bb[4];
      bb[0] = gexcl; bb[1] = bb[0] + cv[0]; bb[2] = bb[1] + cv[1]; bb[3] = bb[2] + cv[2];
      #pragma unroll
      for (int i = 0; i < 4; ++i) {
        if (cv[i] > 0u) {
          #pragma unroll
          for (int r = 0; r < 4; ++r) {
            if (bb[i] <= KR[r] && KR[r] < bb[i] + cv[i]) {
              tbin[r] = 4 * tid + i; tbase[r] = bb[i]; tcnt[r] = cv[i];
            }
          }
        }
      }
      __syncthreads();
      // build lists (dedup: add to first list of each distinct bin; tbin non-decreasing)
      unsigned b0 = tbin[0], b1 = tbin[1], b2 = tbin[2], b3 = tbin[3];
      #pragma unroll
      for (int k = 0; k < 4; ++k) {
        unsigned bk = bin[k], uv = uval[k];
        if (bk == b0) { unsigned s = atomicAdd(&lcnt[0], 1u); if (s < 256u) lists[0][s] = uv; }
        else if (bk == b1 && b1 != b0) { unsigned s = atomicAdd(&lcnt[1], 1u); if (s < 256u) lists[1][s] = uv; }
        else if (bk == b2 && b2 != b1) { unsigned s = atomicAdd(&lcnt[2], 1u); if (s < 256u) lists[2][s] = uv; }
        else if (bk == b3 && b3 != b2) { unsigned s = atomicAdd(&lcnt[3], 1u); if (s < 256u) lists[3][s] = uv; }
      }
      __syncthreads();
      {   // wave j resolves rank j (all 4 waves busy)
        const int j = wid;
        int src = j;
        while (src > 0 && tbin[src - 1] == tbin[j]) --src;   // uniform per wave
        unsigned c = tcnt[j];
        if (c <= 256u) {
          unsigned kk = KR[j] - tbase[j];
          for (int bi = 0; bi < (int)c; bi += 64) {
            int i = bi + lane;
            if (i < (int)c) {
              unsigned e = lists[src][i];
              unsigned r = 0;
              for (int q = 0; q < (int)c; ++q) {
                unsigned x = lists[src][q];
                r += (x < e || (x == e && q < i)) ? 1u : 0u;
              }
              if (r == kk) { resv[j] = e; resf[j] = 1u; }
            }
          }
        }
      }
      __syncthreads();
      // rare exact refine for any unresolved rank (degenerate duplicate-heavy bins)
      for (int j = 0; j < 4; ++j) {
        if (resf[j]) continue;   // uniform (LDS, post-sync)
        bool inj[4];
        #pragma unroll
        for (int k = 0; k < 4; ++k) inj[k] = (bin[k] == tbin[j]);
        unsigned krem = KR[j] - tbase[j];
        for (int iter = 0; iter < 40; ++iter) {
          if (tid == 0) { rmm[0] = 0xFFFFFFFFu; rmm[1] = 0u; }
          __syncthreads();
          #pragma unroll
          for (int k = 0; k < 4; ++k)
            if (inj[k]) { atomicMin(&rmm[0], uval[k]); atomicMax(&rmm[1], uval[k]); }
          __syncthreads();
          unsigned wlo = rmm[0], whi = rmm[1];
          if (wlo == whi) { if (tid == 0) { resv[j] = wlo; resf[j] = 1u; } __syncthreads(); break; }
          *(uint4*)&h[4 * tid] = make_uint4(0u, 0u, 0u, 0u);
          __syncthreads();
          ull rng2 = (ull)whi - (ull)wlo + 1ull;
          ull inv2 = (1ull << 40) / rng2;
          unsigned nb[4];
          #pragma unroll
          for (int k = 0; k < 4; ++k) {
            nb[k] = inj[k] ? (unsigned)((((ull)(uval[k] - wlo)) * inv2) >> 30) : 0u;
            if (inj[k]) atomicAdd(&h[nb[k]], 1u);
          }
          __syncthreads();
          uint4 hc2 = *(const uint4*)&h[4 * tid];
          unsigned s42 = hc2.x + hc2.y + hc2.z + hc2.w;
          unsigned incl2 = s42;
          #pragma unroll
          for (int d = 1; d < 64; d <<= 1) {
            unsigned vv = __shfl_up(incl2, d);
            if (lane >= d) incl2 += vv;
          }
          if (lane == 63) wsum[wid] = incl2;
          if (tid == 0) lcnt[0] = 0u;
          __syncthreads();
          unsigned woff2 = 0u;
          for (int w = 0; w < 4; ++w) if (w < wid) woff2 += wsum[w];
          unsigned gexcl2 = woff2 + incl2 - s42;
          unsigned cv2[4] = {hc2.x, hc2.y, hc2.z, hc2.w};
          unsigned bb2[4];
          bb2[0] = gexcl2; bb2[1] = bb2[0] + cv2[0]; bb2[2] = bb2[1] + cv2[1]; bb2[3] = bb2[2] + cv2[2];
          #pragma unroll
          for (int i = 0; i < 4; ++i) {
            if (cv2[i] > 0u && bb2[i] <= krem && krem < bb2[i] + cv2[i]) {
              t2[0] = 4 * tid + i; t2[1] = bb2[i]; t2[2] = cv2[i];
            }
          }
          __syncthreads();
          unsigned nbin = t2[0], nbase = t2[1], ncnt = t2[2];
          bool newin[4];
          #pragma unroll
          for (int k = 0; k < 4; ++k) newin[k] = inj[k] && (nb[k] == nbin);
          if (ncnt <= 256u) {
            #pragma unroll
            for (int k = 0; k < 4; ++k)
              if (newin[k]) { unsigned s = atomicAdd(&lcnt[0], 1u); if (s < 256u) lists[0][s] = uval[k]; }
            __syncthreads();
            if (wid == 0) {
              unsigned kk2 = krem - nbase;
              for (int bi = 0; bi < (int)ncnt; bi += 64) {
                int i = bi + lane;
                if (i < (int)ncnt) {
                  unsigned e = lists[0][i];
                  unsigned r = 0;
                  for (int q = 0; q < (int)ncnt; ++q) {
                    unsigned x = lists[0][q];
                    r += (x < e || (x == e && q < i)) ? 1u : 0u;
                  }
                  if (r == kk2) { resv[j] = e; resf[j] = 1u; }
                }
              }
            }
            __syncthreads();
            break;
          }
          #pragma unroll
          for (int k = 0; k < 4; ++k) inj[k] = newin[k];
          krem -= nbase;
        }
      }
    } else {
      if (tid < 4) { resv[tid] = lo; resf[tid] = 1u; }
      __syncthreads();
    }

    // ---------------- tau publish: fan out to all 128 consumer mailboxes ----------
    {
      // resv[] visible to all threads (post-sync). All threads compute both taus.
      float s255 = __uint_as_float(resv[0]);
      float s256 = __uint_as_float(resv[1]);
      float s767 = __uint_as_float(resv[2]);
      float s768 = __uint_as_float(resv[3]);
      float tb = 0.75f * s767 + 0.25f * s768;           // quantile(score, .75)
      float tc = -(0.75f * s256 + 0.25f * s255);        // quantile(-score, .75)
      int c = tid & 127;                                // consumer WG
      ull w = (tid < 128)
            ? ((want << 32) | (ull)__float_as_uint(tb))
            : ((want << 32) | (ull)__float_as_uint(tc));
      int slot = (tid < 128) ? wg : (128 + wg);
      st64(&taubox[(ull)c * 256 + slot], w);
    }

    // ---------------- tau gather: poll OWN mailbox (sole reader) -> LDS ----------
    {
      const ull* src = &taubox[(ull)wg * 256 + tid];
      ull v2 = ld64(src);
      while ((v2 >> 32) != want) { __builtin_amdgcn_s_sleep(1); v2 = ld64(src); }
      tauLds[tid] = __uint_as_float((unsigned)v2);
    }
    __syncthreads();

    // ---------------- Phase 3: gates, s-updates, events, theta/corr, reentry ----------
    float gB[4];
    float e0 = 0.f, e1 = 0.f;
    #pragma unroll
    for (int k = 0; k < 4; ++k) {
      float tb = tauLds[rg + 32 * k];
      float tc = tauLds[128 + rg + 32 * k];
      float sc = score[k];                   // own score
      gB[k] = 1.0f / (1.0f + expf(-5.0f * (sc - tb)));
      float gC = 1.0f / (1.0f + expf(-5.0f * (-sc - tc)));
      sB[k] = lf * sB[k] + proj[k] * gB[k];
      sC[k] = lf * sC[k] + proj[k] * gC;
      e0 += (sB[k] >= theta) ? 1.0f : 0.0f;   // old theta
      e1 += (sC[k] >= theta) ? 1.0f : 0.0f;
    }
    #pragma unroll
    for (int m = 8; m < 64; m <<= 1) {
      e0 += __shfl_xor(e0, m);
      e1 += __shfl_xor(e1, m);
    }
    if (lane < 8) { pev[wid][lane][0] = e0; pev[wid][lane][1] = e1; }
    __syncthreads();
    if (tid < 16) {   // summers
      int sfl = tid >> 1, q = tid & 1;
      evfin[sfl][q] = pev[0][sfl][q] + pev[1][sfl][q] + pev[2][sfl][q] + pev[3][sfl][q];
    }
    __syncthreads();
    float cB = evfin[fl][0];
    float cC = evfin[fl][1];
    float th1 = theta + 0.01f * (cB * 0.0078125f) - 0.01f * (cC * 0.0078125f);
    theta = fminf(fmaxf(th1 - 0.01f * (th1 - 0.1f), 0.01f), 10.0f);
    bool corr = (cB > 0.f);
    #pragma unroll
    for (int k = 0; k < 4; ++k) {
      float fac_re = corr ? (c002 + 0.1f * gB[k]) : 1.0f;
      float fac_im = corr ? s002 : 0.0f;
      X_re[k] = Xm_re[k] * fac_re - Xm_im[k] * fac_im;
      X_im[k] = Xm_re[k] * fac_im + Xm_im[k] * fac_re;
      ur[k] = ur_n[k]; ui[k] = ui_n[k];
    }
  }
}

extern "C" void kernel_launch(void* const* d_in, const int* in_sizes, int n_in,
                              void* d_out, int out_size, void* d_ws, size_t ws_size,
                              hipStream_t stream) {
  const float* in_re = (const float*)d_in[0];
  const float* in_im = (const float*)d_in[1];
  const float* r_re  = (const float*)d_in[2];
  const float* r_im  = (const float*)d_in[3];
  const float* amap  = (const float*)d_in[4];
  const float* lmap  = (const float*)d_in[5];
  float* out = (float*)d_out;
  ull* ws = (ull*)d_ws;
  // zero all tag words (score + mailboxes) so no stale tag can match
  hipMemsetAsync(d_ws, 0, (size_t)(BF + 128 * 256) * 8, stream);
  hipLaunchKernelGGL(ResonatorABC_82094004896068_kernel,
                     dim3(NWG), dim3(NTH), 0, stream,
                     in_re, in_im, r_re, r_im, amap, lmap, out, ws);
}